// Round 2
// baseline (182.838 us; speedup 1.0000x reference)
//
#include <hip/hip_runtime.h>

#define BB 4096
#define TT 10
#define SS 301
#define HH 5
#define OO 3

__device__ __forceinline__ float rcp_hw(float x) { return __builtin_amdgcn_rcpf(x); }

// Eigen-style minimax rational tanh on clamped |x|<=9 (rel err ~1e-6).
// p: odd deg-13 numerator, q: even deg-6 denominator, both in u = x^2.
#define TA1  4.89352455891786e-03f
#define TA3  6.37261928875436e-04f
#define TA5  1.48572235717979e-05f
#define TA7  5.12229709037114e-08f
#define TA9  -8.60467152213735e-11f
#define TA11 2.00018790482477e-13f
#define TA13 -2.76076847742355e-16f
#define TB0  4.89352518554385e-03f
#define TB2  2.26843463243900e-03f
#define TB4  1.18534705686654e-04f
#define TB6  1.19825839466702e-06f

__device__ __forceinline__ float tanh_rat(float x) {
    x = fminf(fmaxf(x, -9.0f), 9.0f);          // v_med3
    float u = x * x;
    float p = __fmaf_rn(TA13, u, TA11);
    p = __fmaf_rn(p, u, TA9);
    p = __fmaf_rn(p, u, TA7);
    p = __fmaf_rn(p, u, TA5);
    p = __fmaf_rn(p, u, TA3);
    p = __fmaf_rn(p, u, TA1);
    p = p * x;
    float q = __fmaf_rn(TB6, u, TB4);
    q = __fmaf_rn(q, u, TB2);
    q = __fmaf_rn(q, u, TB0);
    return p * rcp_hw(q);
}

// sigmoid(a) where x = a/2 is the PRE-HALVED preactivation:
// sigma(a) = 0.5 + 0.5*tanh(a/2). The 0.5 on the numerator is folded into
// the (compile-time) coefficients: final = fma(p_half*x, rcp(q), 0.5).
__device__ __forceinline__ float sigmoid_halfarg(float x) {
    x = fminf(fmaxf(x, -9.0f), 9.0f);
    float u = x * x;
    float p = __fmaf_rn(0.5f * TA13, u, 0.5f * TA11);
    p = __fmaf_rn(p, u, 0.5f * TA9);
    p = __fmaf_rn(p, u, 0.5f * TA7);
    p = __fmaf_rn(p, u, 0.5f * TA5);
    p = __fmaf_rn(p, u, 0.5f * TA3);
    p = __fmaf_rn(p, u, 0.5f * TA1);
    p = p * x;
    float q = __fmaf_rn(TB6, u, TB4);
    q = __fmaf_rn(q, u, TB2);
    q = __fmaf_rn(q, u, TB0);
    return __fmaf_rn(p, rcp_hw(q), 0.5f);
}

__global__ __launch_bounds__(256) void gru_kernel(
    const float* __restrict__ x,
    const float* __restrict__ w_ih,
    const float* __restrict__ w_hh,
    const float* __restrict__ b_ih,
    const float* __restrict__ b_hh,
    const float* __restrict__ fc_w,
    const float* __restrict__ fc_b,
    float* __restrict__ out)
{
    const int n = blockIdx.x * blockDim.x + threadIdx.x;
    const int b = n / SS;
    const int s = n - b * SS;
    if (b >= BB) return;

    // Wave-uniform weights: compiler emits scalar loads into SGPRs.
    // r,z rows (g < 2H) are PRE-HALVED so their preacts are a/2, feeding
    // sigmoid_halfarg directly (sigma(a) = 0.5 + 0.5*tanh(a/2)).
    float wih[3 * HH];
    float whh[3 * HH][HH];
    float brz[2 * HH];   // 0.5*(b_ih + b_hh) for r,z gates
    float bin[HH];       // b_ih for n gate (outside r*)
    float bhn[HH];       // b_hh for n gate (inside r*)

    #pragma unroll
    for (int g = 0; g < 2 * HH; ++g) {
        brz[g] = 0.5f * (b_ih[g] + b_hh[g]);
        wih[g] = 0.5f * w_ih[g];   // I == 1
        #pragma unroll
        for (int k = 0; k < HH; ++k) whh[g][k] = 0.5f * w_hh[g * HH + k];
    }
    #pragma unroll
    for (int j = 0; j < HH; ++j) {
        const int g = 2 * HH + j;
        bin[j] = b_ih[g];
        bhn[j] = b_hh[g];
        wih[g] = w_ih[g];
        #pragma unroll
        for (int k = 0; k < HH; ++k) whh[g][k] = w_hh[g * HH + k];
    }

    // Preload all 10 inputs for this sample (coalesced across the wave per t).
    float xt[TT];
    const float* xp = x + (size_t)b * (TT * SS) + s;
    #pragma unroll
    for (int t = 0; t < TT; ++t) xt[t] = xp[t * SS];

    float h[HH];
    #pragma unroll
    for (int j = 0; j < HH; ++j) h[j] = 0.0f;

    #pragma unroll
    for (int t = 0; t < TT; ++t) {
        float hn[HH];
        #pragma unroll
        for (int j = 0; j < HH; ++j) {
            float ar  = __fmaf_rn(xt[t], wih[j],          brz[j]);          // half-preact
            float az  = __fmaf_rn(xt[t], wih[HH + j],     brz[HH + j]);     // half-preact
            float ain = __fmaf_rn(xt[t], wih[2 * HH + j], bin[j]);
            float ahn = bhn[j];
            #pragma unroll
            for (int k = 0; k < HH; ++k) {
                ar  = __fmaf_rn(whh[j][k],          h[k], ar);
                az  = __fmaf_rn(whh[HH + j][k],     h[k], az);
                ahn = __fmaf_rn(whh[2 * HH + j][k], h[k], ahn);
            }
            float r  = sigmoid_halfarg(ar);
            float z  = sigmoid_halfarg(az);
            float nv = tanh_rat(__fmaf_rn(r, ahn, ain));
            // (1-z)*nv + z*h = z*(h - nv) + nv
            hn[j] = __fmaf_rn(z, h[j] - nv, nv);
        }
        #pragma unroll
        for (int j = 0; j < HH; ++j) h[j] = hn[j];
    }

    // y = fc(h); out[(b*O + o)*S + s]
    float* op = out + (size_t)b * (OO * SS) + s;
    #pragma unroll
    for (int o = 0; o < OO; ++o) {
        float y = fc_b[o];
        #pragma unroll
        for (int k = 0; k < HH; ++k) y = __fmaf_rn(fc_w[o * HH + k], h[k], y);
        op[o * SS] = y;
    }
}

extern "C" void kernel_launch(void* const* d_in, const int* in_sizes, int n_in,
                              void* d_out, int out_size, void* d_ws, size_t ws_size,
                              hipStream_t stream) {
    const float* x    = (const float*)d_in[0];
    const float* w_ih = (const float*)d_in[1];
    const float* w_hh = (const float*)d_in[2];
    const float* b_ih = (const float*)d_in[3];
    const float* b_hh = (const float*)d_in[4];
    const float* fc_w = (const float*)d_in[5];
    const float* fc_b = (const float*)d_in[6];
    float* out = (float*)d_out;

    const int N = BB * SS;                 // 1,232,896
    const int block = 256;
    const int grid = (N + block - 1) / block;  // 4816 exactly
    gru_kernel<<<grid, block, 0, stream>>>(x, w_ih, w_hh, b_ih, b_hh, fc_w, fc_b, out);
}